// Round 12
// baseline (477.484 us; speedup 1.0000x reference)
//
#include <hip/hip_runtime.h>
#include <hip/hip_bf16.h>
#include <stdint.h>

// FusedLinearCrossEntropyLoss on MI355X (gfx950)
// loss = mean_i( logsumexp_j(x_i . w_j + b_j) - (x_i . w_t(i) + b_t(i)) )
//
// R16: W-IN-LDS READ-ONLY CACHE + BARRIER-FREE K-LOOP + PERSISTENT BLOCKS.
//   Diagnosis: all no-LDS variants are per-CU operand-delivery bound (each
//   byte crosses L1/L2->CU once PER WAVE; 2-3:1 mem:compute -> 35% MfmaUtil;
//   R15 proved L2-miss BW is NOT binding: 4x FETCH cost only 12%). LDS fixes
//   delivery but per-kg barriers killed R7/R8. New structure: W panel (128KB,
//   read-only) staged ONCE per block -> K-loop has NO barriers at all.
//   Persistent: grid=250 (1 block/panel, 512 thr, 1/CU), each loops 16 slabs;
//   W fetched from HBM exactly once machine-wide (32MB). A-frags stream from
//   global; 4 waves share each A frag -> L1 absorbs duplicates (16KB/kg set);
//   raw s_barrier every 4 kg = drift bound only (no drain, no data hazard).
//   B-frags from LDS (128B/cy pipe). Per wave: 128x32 out, acc=64 AGPR.
//
// Chunk layout (contiguous 32B/lane): chunk c = R*16 + g. lane l, byte b:
//   data[c*2048 + l*32 + b] = M[R*32 + (l&31)][g*64 + (l>>5)*32 + b]

typedef float f16v __attribute__((ext_vector_type(16)));
typedef int v8i __attribute__((ext_vector_type(8)));
typedef int v4i __attribute__((ext_vector_type(4)));

__device__ __forceinline__ unsigned pk_fp8(float4 v) {
  int w = 0;
  w = __builtin_amdgcn_cvt_pk_fp8_f32(v.x, v.y, w, false);  // bytes 0,1
  w = __builtin_amdgcn_cvt_pk_fp8_f32(v.z, v.w, w, true);   // bytes 2,3
  return (unsigned)w;
}

// fp32 [N x 1024] -> fp8 fragment chunks via LDS staging (R14, verified).
__global__ __launch_bounds__(256) void cast_stage_k(const float* __restrict__ inW,
                                                    char* __restrict__ outW,
                                                    const float* __restrict__ inX,
                                                    char* __restrict__ outX,
                                                    int sW, int sTot) {
  __shared__ unsigned lds[8192];  // 32 KB
  int s = blockIdx.x;
  const float* in;
  char* out;
  if (s < sW) { in = inW; out = outW; }
  else        { in = inX; out = outX; s -= sW; }
  const int t = threadIdx.x;
  const float4* src = (const float4*)in + (long)s * 8192 + t;
  const int u0 = ((t >> 3) << 8) + (t & 7);
#pragma unroll 4
  for (int r = 0; r < 32; ++r) lds[u0 + r * 8] = pk_fp8(src[r * 256]);
  __syncthreads();
  const uint4* lv = (const uint4*)lds;
  uint4* dst = (uint4*)(out + (long)s * 32768);
#pragma unroll
  for (int p = 0; p < 8; ++p) dst[p * 256 + t] = lv[p * 256 + t];
}

// Load one 32B/lane fragment (two adjacent dwordx4 -> v8i). Works for both
// global (buffer/global_load) and LDS (ds_read_b128) pointers.
__device__ __forceinline__ v8i ldfrag(const char* p) {
  const v4i* q = (const v4i*)p;
  v4i lo = q[0];
  v4i hi = q[1];
  return __builtin_shufflevector(lo, hi, 0, 1, 2, 3, 4, 5, 6, 7);
}

#define MFMA1(A, B, C) \
  __builtin_amdgcn_mfma_scale_f32_32x32x64_f8f6f4(A, B, C, 0, 0, 0, 127, 0, 127)

// Persistent block per 128-col panel. 8 waves (2 wr x 4 wc); per wave
// 128x32 output via 4x1 of 32x32x64. W panel in LDS (read-only after one
// prologue barrier); K-loop barrier-free. 16 row-slabs per block.
__global__ __launch_bounds__(512, 2)
void gemm_sumexp(const char* __restrict__ Xf, const char* __restrict__ Wf,
                 const float* __restrict__ bias, float* __restrict__ partials,
                 int H, int BT) {
  __shared__ char wlds[131072];          // 128 KB W panel
  __shared__ float rowsum[2][4][256];    // 8 KB, double-buffered per slab

  const int tid = threadIdx.x;
  const int w = tid >> 6, lane = tid & 63;
  const int wr = w >> 2, wc = w & 3;
  const int l32 = lane & 31, kh = lane >> 5;

  const int by = blockIdx.x;             // panel id, 0..nCB-1
  const int n0 = by * 128;

  // ---- stage W panel: 128 KB contiguous (chunk rows by*4..by*4+3) ----
  {
    const char* src = Wf + (long)by * 131072 + lane * 16;
#pragma unroll
    for (int r = 0; r < 16; ++r) {
      const int i = w * 16 + r;
      __builtin_amdgcn_global_load_lds(
          (const __attribute__((address_space(1))) void*)(src + i * 1024),
          (__attribute__((address_space(3))) void*)(wlds + i * 1024),
          16, 0, 0);
    }
  }
  __syncthreads();  // drains vmcnt; W is read-only from here on

  const float bv = bias[n0 + wc * 32 + l32];
  const int nG = H >> 6;                 // 16 k-groups
  const int nSlab = BT >> 8;             // 16 row-slabs of 256

  for (int s = 0; s < nSlab; ++s) {
    f16v acc[4];
#pragma unroll
    for (int mi = 0; mi < 4; mi++)
#pragma unroll
      for (int r = 0; r < 16; r++) acc[mi][r] = 0.f;

    const int Rb = s * 8 + wr * 4;       // A chunk-row base for this wave
    const char* pA0 = Xf + (long)(Rb + 0) * 32768 + lane * 32;
    const char* pA1 = Xf + (long)(Rb + 1) * 32768 + lane * 32;
    const char* pA2 = Xf + (long)(Rb + 2) * 32768 + lane * 32;
    const char* pA3 = Xf + (long)(Rb + 3) * 32768 + lane * 32;
    const char* pB = wlds + wc * 32768 + lane * 32;

#pragma unroll 4
    for (int g = 0; g < nG; ++g) {
      v8i b0 = ldfrag(pB);  pB += 2048;
      v8i a0 = ldfrag(pA0); pA0 += 2048;
      v8i a1 = ldfrag(pA1); pA1 += 2048;
      v8i a2 = ldfrag(pA2); pA2 += 2048;
      v8i a3 = ldfrag(pA3); pA3 += 2048;
      acc[0] = MFMA1(a0, b0, acc[0]);
      acc[1] = MFMA1(a1, b0, acc[1]);
      acc[2] = MFMA1(a2, b0, acc[2]);
      acc[3] = MFMA1(a3, b0, acc[3]);
      if ((g & 3) == 3) __builtin_amdgcn_s_barrier();  // drift bound only
    }
    pB -= (long)nG * 2048;               // B repeats every slab

    // ---- epilogue for this slab ----
    // C/D 32x32 layout: col = lane&31, row = (reg&3)+8*(reg>>2)+4*(lane>>5)
    const int sb = s & 1;
#pragma unroll
    for (int mi = 0; mi < 4; mi++) {
      float p[16];
#pragma unroll
      for (int r = 0; r < 16; r++) p[r] = __expf(acc[mi][r] + bv);
#pragma unroll
      for (int off = 1; off < 32; off <<= 1)
#pragma unroll
        for (int r = 0; r < 16; r++) p[r] += __shfl_xor(p[r], off, 32);
      if (l32 == 0) {
#pragma unroll
        for (int r = 0; r < 16; r++)
          rowsum[sb][wc][wr * 128 + mi * 32 + (r & 3) + 8 * (r >> 2) + 4 * kh] = p[r];
      }
    }
    __syncthreads();
    if (tid < 256)
      partials[(long)by * BT + s * 256 + tid] =
          rowsum[sb][0][tid] + rowsum[sb][1][tid] +
          rowsum[sb][2][tid] + rowsum[sb][3][tid];
  }
}

// Fused per-row finish: S = sum of panel partials; x_y = x[row].W[t] + b[t]
// (exact fp32); pr = log(S) - x_y. One wave per row.
__global__ __launch_bounds__(256)
void row_reduce(const float* __restrict__ partials, const float* __restrict__ x,
                const float* __restrict__ wt, const float* __restrict__ bias,
                const int* __restrict__ tgt, float* __restrict__ bsum,
                float* __restrict__ bcnt, int BT, int nCB, int H, int V) {
  const int w = threadIdx.x >> 6, lane = threadIdx.x & 63;
  const int row = blockIdx.x * 4 + w;
  float S = 0.f;
  for (int b = lane; b < nCB; b += 64) S += partials[(long)b * BT + row];
  const int t = tgt[row];
  const int st = min(max(t, 0), V - 1);
  const float4* xr = (const float4*)(x + (long)row * H);
  const float4* wr = (const float4*)(wt + (long)st * H);
  float d = 0.f;
  const int n4 = H >> 2;
  for (int i = lane; i < n4; i += 64) {
    float4 a = xr[i], b = wr[i];
    d += a.x * b.x + a.y * b.y + a.z * b.z + a.w * b.w;
  }
  for (int off = 32; off; off >>= 1) {
    S += __shfl_down(S, off, 64);
    d += __shfl_down(d, off, 64);
  }
  __shared__ float sp[4], sc[4];
  if (lane == 0) {
    bool valid = (t != -100);
    sp[w] = valid ? (logf(S) - (d + bias[st])) : 0.f;
    sc[w] = valid ? 1.f : 0.f;
  }
  __syncthreads();
  if (threadIdx.x == 0) {
    bsum[blockIdx.x] = sp[0] + sp[1] + sp[2] + sp[3];
    bcnt[blockIdx.x] = sc[0] + sc[1] + sc[2] + sc[3];
  }
}

__global__ void finalize(const float* __restrict__ bsum, const float* __restrict__ bcnt,
                         float* __restrict__ out, int nb) {
  float s = 0.f, c = 0.f;
  for (int i = threadIdx.x; i < nb; i += 64) { s += bsum[i]; c += bcnt[i]; }
  for (int off = 32; off; off >>= 1) {
    s += __shfl_down(s, off, 64);
    c += __shfl_down(c, off, 64);
  }
  if (threadIdx.x == 0) out[0] = s / c;
}

extern "C" void kernel_launch(void* const* d_in, const int* in_sizes, int n_in,
                              void* d_out, int out_size, void* d_ws, size_t ws_size,
                              hipStream_t stream) {
  const float* x = (const float*)d_in[0];
  const int* tgt = (const int*)d_in[1];
  const float* w = (const float*)d_in[2];
  const float* bias = (const float*)d_in[3];
  float* out = (float*)d_out;

  const int BT = in_sizes[1];            // 4096
  const int V = in_sizes[3];             // 32000
  const int H = in_sizes[0] / BT;        // 1024
  const int nCB = V / 128;               // 250 column panels

  char* ws = (char*)d_ws;
  const long wb_bytes = (long)V * H;     // fp8: 1 B/elem
  const long xb_bytes = (long)BT * H;
  char* Wf = ws;
  char* Xf = ws + wb_bytes;
  float* partials = (float*)(ws + wb_bytes + xb_bytes);
  float* bsum = partials + (long)nCB * BT;
  float* bcnt = bsum + (BT / 4);

  const int sW = V / 32;                 // 1000 W stripes
  const int sTot = sW + BT / 32;         // + 128 X stripes
  cast_stage_k<<<sTot, 256, 0, stream>>>(w, Wf, x, Xf, sW, sTot);
  gemm_sumexp<<<nCB, 512, 0, stream>>>(Xf, Wf, bias, partials, H, BT);
  row_reduce<<<BT / 4, 256, 0, stream>>>(partials, x, w, bias, tgt, bsum, bcnt,
                                         BT, nCB, H, V);
  finalize<<<1, 64, 0, stream>>>(bsum, bcnt, out, BT / 4);
}

// Round 13
// 386.520 us; speedup vs baseline: 1.2353x; 1.2353x over previous
//
#include <hip/hip_runtime.h>
#include <hip/hip_bf16.h>
#include <stdint.h>

// FusedLinearCrossEntropyLoss on MI355X (gfx950)
// loss = mean_i( logsumexp_j(x_i . w_j + b_j) - (x_i . w_t(i) + b_t(i)) )
//
// R17: R12/R14 config (best: 372.5us; gemm 162.4 = 1653 TF) + the one
//      untested pipelining cell: UNROLL-2 BATCHED LOADS, acc=64, NO GUARDS.
//      Spill matrix so far: R9 acc=128 demand 249/256 -> spill; R13 guards
//      (if(h2) mid-body) -> spill at VGPR 84; R12 acc=64 serial -> no spill,
//      compiler holds ONE operand set (VGPR 56) and exposes ~600cy/kg.
//      This cell: 8 unconditional loads (kg g and g+1) at body top, then 8
//      MFMAs. Demand ~= 64 acc + 64 ops + 20 addr = 148 <= 170 @ (256,3).
//      nG=16 even -> no tail, no guards, no cross-iteration state.
//      First MFMA waits vmcnt(4) (g+1's loads in flight) -> exposure halved.
//      Tripwire: WRITE_SIZE >> 10MB = 4th spill = R12 is the ceiling.
//      R16 reverted (W-in-LDS cost occupancy 41->22%, lost 120us; its FETCH
//      win was irrelevant: R15/R16 proved fetch volume doesn't bind time).
//
// Chunk layout (contiguous 32B/lane): chunk c = R*16 + g. lane l, byte b:
//   data[c*2048 + l*32 + b] = M[R*32 + (l&31)][g*64 + (l>>5)*32 + b]

typedef float f16v __attribute__((ext_vector_type(16)));
typedef int v8i __attribute__((ext_vector_type(8)));
typedef int v4i __attribute__((ext_vector_type(4)));

__device__ __forceinline__ unsigned pk_fp8(float4 v) {
  int w = 0;
  w = __builtin_amdgcn_cvt_pk_fp8_f32(v.x, v.y, w, false);  // bytes 0,1
  w = __builtin_amdgcn_cvt_pk_fp8_f32(v.z, v.w, w, true);   // bytes 2,3
  return (unsigned)w;
}

// fp32 [N x 1024] -> fp8 fragment chunks via LDS staging (R14, verified).
__global__ __launch_bounds__(256) void cast_stage_k(const float* __restrict__ inW,
                                                    char* __restrict__ outW,
                                                    const float* __restrict__ inX,
                                                    char* __restrict__ outX,
                                                    int sW, int sTot) {
  __shared__ unsigned lds[8192];  // 32 KB
  int s = blockIdx.x;
  const float* in;
  char* out;
  if (s < sW) { in = inW; out = outW; }
  else        { in = inX; out = outX; s -= sW; }
  const int t = threadIdx.x;
  const float4* src = (const float4*)in + (long)s * 8192 + t;
  const int u0 = ((t >> 3) << 8) + (t & 7);
#pragma unroll 4
  for (int r = 0; r < 32; ++r) lds[u0 + r * 8] = pk_fp8(src[r * 256]);
  __syncthreads();
  const uint4* lv = (const uint4*)lds;
  uint4* dst = (uint4*)(out + (long)s * 32768);
#pragma unroll
  for (int p = 0; p < 8; ++p) dst[p * 256 + t] = lv[p * 256 + t];
}

// Load one 32B/lane fragment (two adjacent dwordx4 -> v8i).
__device__ __forceinline__ v8i ldfrag(const char* p) {
  const v4i* q = (const v4i*)p;
  v4i lo = q[0];
  v4i hi = q[1];
  return __builtin_shufflevector(lo, hi, 0, 1, 2, 3, 4, 5, 6, 7);
}

#define MFMA1(A, B, C) \
  __builtin_amdgcn_mfma_scale_f32_32x32x64_f8f6f4(A, B, C, 0, 0, 0, 127, 0, 127)

// 128x128 block tile, 4 waves in 2x2; each wave 64x64 via 2x2 of 32x32x64.
// No LDS staging, no barriers; unroll-2 batched loads (see header).
__global__ __launch_bounds__(256, 3)
void gemm_sumexp(const char* __restrict__ Xf, const char* __restrict__ Wf,
                 const float* __restrict__ bias, float* __restrict__ partials,
                 int H, int BT) {
  __shared__ float rowsum[2][128];

  const int tid = threadIdx.x;
  const int w = tid >> 6, lane = tid & 63;
  const int wr = w >> 1, wc = w & 1;
  const int l32 = lane & 31, kh = lane >> 5;

  const int bx = blockIdx.x;   // row-blocks fast-varying (W panel L2 sharing)
  const int by = blockIdx.y;
  const int m0 = bx * 128, n0 = by * 128;

  const int Rb = bx * 4 + wr * 2;   // A 32-row block base
  const int Nb = by * 4 + wc * 2;   // B 32-row block base

  const char* pA0 = Xf + (long)(Rb + 0) * 32768 + lane * 32;
  const char* pA1 = Xf + (long)(Rb + 1) * 32768 + lane * 32;
  const char* pB0 = Wf + (long)(Nb + 0) * 32768 + lane * 32;
  const char* pB1 = Wf + (long)(Nb + 1) * 32768 + lane * 32;

  f16v acc[2][2];
#pragma unroll
  for (int mi = 0; mi < 2; mi++)
#pragma unroll
    for (int ni = 0; ni < 2; ni++)
#pragma unroll
      for (int r = 0; r < 16; r++) acc[mi][ni][r] = 0.f;

  const int nG = H >> 6;  // 16 k-groups of 64 (even -> no tail)

#pragma unroll 1
  for (int g = 0; g < nG; g += 2) {
    // 8 unconditional loads: kg g then kg g+1. Compiler waitcnt before the
    // first MFMA leaves kg g+1's 4 loads outstanding (counted, not drained).
    v8i a0 = ldfrag(pA0);
    v8i a1 = ldfrag(pA1);
    v8i b0 = ldfrag(pB0);
    v8i b1 = ldfrag(pB1);
    v8i c0 = ldfrag(pA0 + 2048);
    v8i c1 = ldfrag(pA1 + 2048);
    v8i d0 = ldfrag(pB0 + 2048);
    v8i d1 = ldfrag(pB1 + 2048);
    pA0 += 4096; pA1 += 4096; pB0 += 4096; pB1 += 4096;
    acc[0][0] = MFMA1(a0, b0, acc[0][0]);
    acc[0][1] = MFMA1(a0, b1, acc[0][1]);
    acc[1][0] = MFMA1(a1, b0, acc[1][0]);
    acc[1][1] = MFMA1(a1, b1, acc[1][1]);
    acc[0][0] = MFMA1(c0, d0, acc[0][0]);
    acc[0][1] = MFMA1(c0, d1, acc[0][1]);
    acc[1][0] = MFMA1(c1, d0, acc[1][0]);
    acc[1][1] = MFMA1(c1, d1, acc[1][1]);
  }

  // ---- epilogue: per-row sum of exp(logit + bias) ----
  // C/D 32x32 layout: col = lane&31, row = (reg&3) + 8*(reg>>2) + 4*(lane>>5)
  float bv[2];
  bv[0] = bias[n0 + wc * 64 + l32];
  bv[1] = bias[n0 + wc * 64 + 32 + l32];

#pragma unroll
  for (int mi = 0; mi < 2; mi++) {
    float p[16];
#pragma unroll
    for (int r = 0; r < 16; r++) p[r] = 0.f;
#pragma unroll
    for (int ni = 0; ni < 2; ni++)
#pragma unroll
      for (int r = 0; r < 16; r++) p[r] += __expf(acc[mi][ni][r] + bv[ni]);
    // reduce across the 32 columns (lanes within each 32-group)
#pragma unroll
    for (int off = 1; off < 32; off <<= 1)
#pragma unroll
      for (int r = 0; r < 16; r++) p[r] += __shfl_xor(p[r], off, 32);
    if (l32 == 0) {
#pragma unroll
      for (int r = 0; r < 16; r++)
        rowsum[wc][wr * 64 + mi * 32 + (r & 3) + 8 * (r >> 2) + 4 * kh] = p[r];
    }
  }
  __syncthreads();
  if (tid < 128)
    partials[(long)by * BT + m0 + tid] = rowsum[0][tid] + rowsum[1][tid];
}

// Fused per-row finish: S = sum of panel partials; x_y = x[row].W[t] + b[t]
// (exact fp32); pr = log(S) - x_y. One wave per row.
__global__ __launch_bounds__(256)
void row_reduce(const float* __restrict__ partials, const float* __restrict__ x,
                const float* __restrict__ wt, const float* __restrict__ bias,
                const int* __restrict__ tgt, float* __restrict__ bsum,
                float* __restrict__ bcnt, int BT, int nCB, int H, int V) {
  const int w = threadIdx.x >> 6, lane = threadIdx.x & 63;
  const int row = blockIdx.x * 4 + w;
  float S = 0.f;
  for (int b = lane; b < nCB; b += 64) S += partials[(long)b * BT + row];
  const int t = tgt[row];
  const int st = min(max(t, 0), V - 1);
  const float4* xr = (const float4*)(x + (long)row * H);
  const float4* wr = (const float4*)(wt + (long)st * H);
  float d = 0.f;
  const int n4 = H >> 2;
  for (int i = lane; i < n4; i += 64) {
    float4 a = xr[i], b = wr[i];
    d += a.x * b.x + a.y * b.y + a.z * b.z + a.w * b.w;
  }
  for (int off = 32; off; off >>= 1) {
    S += __shfl_down(S, off, 64);
    d += __shfl_down(d, off, 64);
  }
  __shared__ float sp[4], sc[4];
  if (lane == 0) {
    bool valid = (t != -100);
    sp[w] = valid ? (logf(S) - (d + bias[st])) : 0.f;
    sc[w] = valid ? 1.f : 0.f;
  }
  __syncthreads();
  if (threadIdx.x == 0) {
    bsum[blockIdx.x] = sp[0] + sp[1] + sp[2] + sp[3];
    bcnt[blockIdx.x] = sc[0] + sc[1] + sc[2] + sc[3];
  }
}

__global__ void finalize(const float* __restrict__ bsum, const float* __restrict__ bcnt,
                         float* __restrict__ out, int nb) {
  float s = 0.f, c = 0.f;
  for (int i = threadIdx.x; i < nb; i += 64) { s += bsum[i]; c += bcnt[i]; }
  for (int off = 32; off; off >>= 1) {
    s += __shfl_down(s, off, 64);
    c += __shfl_down(c, off, 64);
  }
  if (threadIdx.x == 0) out[0] = s / c;
}

extern "C" void kernel_launch(void* const* d_in, const int* in_sizes, int n_in,
                              void* d_out, int out_size, void* d_ws, size_t ws_size,
                              hipStream_t stream) {
  const float* x = (const float*)d_in[0];
  const int* tgt = (const int*)d_in[1];
  const float* w = (const float*)d_in[2];
  const float* bias = (const float*)d_in[3];
  float* out = (float*)d_out;

  const int BT = in_sizes[1];            // 4096
  const int V = in_sizes[3];             // 32000
  const int H = in_sizes[0] / BT;        // 1024
  const int nCB = V / 128;               // 250 column panels

  char* ws = (char*)d_ws;
  const long wb_bytes = (long)V * H;     // fp8: 1 B/elem
  const long xb_bytes = (long)BT * H;
  char* Wf = ws;
  char* Xf = ws + wb_bytes;
  float* partials = (float*)(ws + wb_bytes + xb_bytes);
  float* bsum = partials + (long)nCB * BT;
  float* bcnt = bsum + (BT / 4);

  const int sW = V / 32;                 // 1000 W stripes
  const int sTot = sW + BT / 32;         // + 128 X stripes
  cast_stage_k<<<sTot, 256, 0, stream>>>(w, Wf, x, Xf, sW, sTot);
  dim3 grid(BT / 128, nCB);              // bx fast-varying (R12/R14 order)
  gemm_sumexp<<<grid, 256, 0, stream>>>(Xf, Wf, bias, partials, H, BT);
  row_reduce<<<BT / 4, 256, 0, stream>>>(partials, x, w, bias, tgt, bsum, bcnt,
                                         BT, nCB, H, V);
  finalize<<<1, 64, 0, stream>>>(bsum, bcnt, out, BT / 4);
}